// Round 5
// baseline (6419.208 us; speedup 1.0000x reference)
//
#include <hip/hip_runtime.h>
#include <hip/hip_bf16.h>

typedef __attribute__((ext_vector_type(8))) short  bf16x8;
typedef __attribute__((ext_vector_type(4))) short  s16x4;
typedef __attribute__((ext_vector_type(4))) float  f32x4;

#define LOG2E 1.44269504088896340736f
template<int N> struct ic { static constexpr int v = N; };

__device__ __forceinline__ unsigned short f2bf(float x) {
    union { float f; unsigned int u; } v; v.f = x;
    unsigned int u = v.u;
    u += 0x7fffu + ((u >> 16) & 1u);
    return (unsigned short)(u >> 16);
}
__device__ __forceinline__ float fast_sigmoid(float x) {
    float e = __builtin_amdgcn_exp2f(-LOG2E * x);
    return __builtin_amdgcn_rcpf(1.0f + e);
}
__device__ __forceinline__ float fast_tanh(float x) {
    float e = __builtin_amdgcn_exp2f(2.0f * LOG2E * x);
    return 1.0f - 2.0f * __builtin_amdgcn_rcpf(1.0f + e);
}

// ---------------------------------------------------------------------------
// Pack [1024 x 256] fp32 gate weight into half-split B-fragment layout:
//   fid = ho*256 + w*32 + kk*4 + j   (half ho, wave w, kstep kk, gate j)
//   dst[(fid*64+lane)*8+e] = bf16(W[R][k])
//   R = j*256 + ho*128 + w*16 + (lane&15)
//   k = kk*32 + 4*(lane>>4) + (e&3) + 16*(e>>2)
// ---------------------------------------------------------------------------
__global__ void pack_w_gates(const float* __restrict__ W, unsigned short* __restrict__ dst) {
    int idx  = blockIdx.x * 256 + threadIdx.x;   // 0..32767
    int lane = idx & 63;
    int fid  = idx >> 6;                         // 0..511
    int j    = fid & 3;
    int kk   = (fid >> 2) & 7;
    int w    = (fid >> 5) & 7;
    int ho   = fid >> 8;
    int R    = j * 256 + ho * 128 + w * 16 + (lane & 15);
    int kb   = kk * 32 + 4 * (lane >> 4);
    const float* src = W + (size_t)R * 256 + kb;
    union { unsigned short s[8]; uint4 v; } u;
#pragma unroll
    for (int e = 0; e < 8; ++e) {
        int k = (e & 3) + 16 * (e >> 2);
        u.s[e] = f2bf(src[k]);
    }
    *(uint4*)(dst + (size_t)idx * 8) = u.v;
}

// W_out [128 x 256]: fid = wv*8 + kk, R = wv*16 + (lane&15)
__global__ void pack_w_out(const float* __restrict__ W, unsigned short* __restrict__ dst) {
    int idx  = blockIdx.x * 256 + threadIdx.x;   // 0..4095
    int lane = idx & 63;
    int fid  = idx >> 6;
    int kk   = fid & 7;
    int wv   = fid >> 3;
    int R    = wv * 16 + (lane & 15);
    int kb   = kk * 32 + 4 * (lane >> 4);
    const float* src = W + (size_t)R * 256 + kb;
    union { unsigned short s[8]; uint4 v; } u;
#pragma unroll
    for (int e = 0; e < 8; ++e) {
        int k = (e & 3) + 16 * (e >> 2);
        u.s[e] = f2bf(src[k]);
    }
    *(uint4*)(dst + (size_t)idx * 8) = u.v;
}

__device__ __forceinline__ int aload_acq(const int* p) {
    return __hip_atomic_load(p, __ATOMIC_ACQUIRE, __HIP_MEMORY_SCOPE_AGENT);
}
__device__ __forceinline__ void astore_rel(int* p, int v) {
    __hip_atomic_store(p, v, __ATOMIC_RELEASE, __HIP_MEMORY_SCOPE_AGENT);
}

// ---------------------------------------------------------------------------
// Pair-split persistent LSTM. 256 blocks x 512 thr; block bid owns batch rows
// [pid*16,+16) and gate-column half ho; partner = bid^8 (same XCD). Whh-half
// fully register-resident (128 VGPR/wave). Per step: own-half kk phases,
// then stage partner's h-half from an L2 mailbox (ready/ack handshake),
// partner-half kk phases, fused y GEMM, cell update, publish own h-half.
// LDS 104KB forces 1 block/CU -> all 256 blocks co-resident.
// ---------------------------------------------------------------------------
__global__ __launch_bounds__(512, 2) void lstm_main(
    const float* __restrict__ C,
    const unsigned short* __restrict__ Wih_p,
    const unsigned short* __restrict__ Whh_p,
    const unsigned short* __restrict__ Wout_p,
    const float* __restrict__ b_ih,
    const float* __restrict__ b_hh,
    const float* __restrict__ b_out,
    float* __restrict__ Y,
    unsigned short* __restrict__ mbox,
    int* __restrict__ ready,
    int* __restrict__ ack,
    int T, int Btot)
{
    __shared__ short hbuf[2][16 * 256];     // 16 KB h double-buffer (full K)
    __shared__ short woutl[8][8][512];      // 64 KB W_out frags per wave
    __shared__ volatile float lds_pad[6144];// 24 KB pad -> 104 KB total

    const int tid  = threadIdx.x;
    const int l    = tid & 63;
    const int wid  = tid >> 6;
    const int l15  = l & 15;
    const int g4   = l >> 4;
    const int bid  = blockIdx.x;
    const int ho   = (bid >> 3) & 1;        // gate-col half owned
    const int po   = 1 - ho;
    const int pid  = ((bid >> 4) << 3) | (bid & 7);
    const int row0 = pid * 16;
    const int pt   = bid ^ 8;               // partner block (same XCD)

    if (tid == 0) lds_pad[0] = 0.f;

    unsigned short*       mb_me = mbox + (size_t)bid * 2 * 2048;
    const unsigned short* mb_pt = mbox + (size_t)pt  * 2 * 2048;
    int* rdy_me = ready + bid * 32;
    int* rdy_pt = ready + pt  * 32;
    int* ack_me = ack   + bid * 32;
    int* ack_pt = ack   + pt  * 32;

    const unsigned short* whb = Whh_p + (size_t)(ho * 8 + wid) * 16384;
    const unsigned short* wib = Wih_p + (size_t)(ho * 8 + wid) * 16384;

    // ---- stage C tile -> hbuf[0] (bf16, swizzled 8B slots, full 256 cols) ----
    {
        int r  = tid >> 5;
        int cb = tid & 31;
        const float* src = C + (size_t)(row0 + r) * 256 + cb * 8;
        float4 f0 = *(const float4*)(src);
        float4 f1 = *(const float4*)(src + 4);
        int m  = 9 * (r & 7);
        int s0 = cb * 2;
        short* hb = hbuf[0] + r * 256;
        union { unsigned short s[4]; unsigned long long v; } p0, p1;
        p0.s[0] = f2bf(f0.x); p0.s[1] = f2bf(f0.y); p0.s[2] = f2bf(f0.z); p0.s[3] = f2bf(f0.w);
        p1.s[0] = f2bf(f1.x); p1.s[1] = f2bf(f1.y); p1.s[2] = f2bf(f1.z); p1.s[3] = f2bf(f1.w);
        *(unsigned long long*)(hb + ((s0 ^ m) * 4))       = p0.v;
        *(unsigned long long*)(hb + (((s0 + 1) ^ m) * 4)) = p1.v;
    }

    // ---- stage W_out frags into LDS (wave-private) ----
#pragma unroll
    for (int kk = 0; kk < 8; ++kk) {
        bf16x8 f = *(const bf16x8*)(Wout_p + ((size_t)(wid * 8 + kk) * 64 + l) * 8);
        *(bf16x8*)&woutl[wid][kk][l * 8] = f;
    }

    // ---- Whh-half fragments: fully register resident (128 VGPR) ----
    bf16x8 whr[8][4];
#pragma unroll
    for (int kk = 0; kk < 8; ++kk)
#pragma unroll
        for (int j = 0; j < 4; ++j)
            whr[kk][j] = *(const bf16x8*)(whb + ((size_t)(kk * 4 + j) * 64 + l) * 8);

    // A-frag loader: row = l&15, k = kk*32 + 4*(l>>4) + {0..3,16..19}
    const int msw = 9 * (l15 & 7);
    auto loadA = [&](const short* buf, int kk) -> bf16x8 {
        int slo = kk * 8 + g4;
        const short* base = buf + l15 * 256;
        s16x4 lo = *(const s16x4*)(base + ((slo ^ msw) * 4));
        s16x4 hi = *(const s16x4*)(base + (((slo + 4) ^ msw) * 4));
        bf16x8 a;
        a[0] = lo[0]; a[1] = lo[1]; a[2] = lo[2]; a[3] = lo[3];
        a[4] = hi[0]; a[5] = hi[1]; a[6] = hi[2]; a[7] = hi[3];
        return a;
    };

    __syncthreads();

    // ---- x_gates (one-time): C @ Wih_half^T + biases ----
    f32x4 acc4[4];
#pragma unroll
    for (int j = 0; j < 4; ++j) acc4[j] = (f32x4){0.f, 0.f, 0.f, 0.f};
#pragma unroll
    for (int kk = 0; kk < 8; ++kk) {
        bf16x8 a = loadA(hbuf[0], kk);
#pragma unroll
        for (int j = 0; j < 4; ++j) {
            bf16x8 b = *(const bf16x8*)(wib + ((size_t)(kk * 4 + j) * 64 + l) * 8);
            acc4[j] = __builtin_amdgcn_mfma_f32_16x16x32_bf16(a, b, acc4[j], 0, 0, 0);
        }
    }
    f32x4 xg[4];
#pragma unroll
    for (int j = 0; j < 4; ++j) {
        int gc = j * 256 + ho * 128 + wid * 16 + l15;
        xg[j] = acc4[j] + (b_ih[gc] + b_hh[gc]);
    }

    float cst[4] = {0.f, 0.f, 0.f, 0.f};
    const float by = b_out[wid * 16 + l15];
    const int lc = wid * 16 + l15;          // local half-col
    const int fc = ho * 128 + lc;           // full h-col

    // cell update from acc4 -> write own half to nxtb (swz) + mailbox slot
    auto update = [&](short* nxtb, unsigned short* mbs) {
#pragma unroll
        for (int rr = 0; rr < 4; ++rr) {
            float iv = fast_sigmoid(acc4[0][rr]);
            float fv = fast_sigmoid(acc4[1][rr]);
            float gv = fast_tanh(acc4[2][rr]);
            float ov = fast_sigmoid(acc4[3][rr]);
            float cn = fv * cst[rr] + iv * gv;
            cst[rr] = cn;
            float hn = ov * fast_tanh(cn);
            unsigned short hb = f2bf(hn);
            int row = 4 * g4 + rr;
            int s   = fc >> 2;
            nxtb[row * 256 + ((s ^ (9 * (row & 7))) << 2) + (fc & 3)] = (short)hb;
            mbs[row * 128 + lc] = hb;
        }
    };

    // stage partner mailbox slot -> dst LDS buffer partner cols (swizzled)
    auto stage_partner = [&](short* dstb, const unsigned short* mbs) {
        int row = 2 * wid + (l >> 5);       // wave w covers rows 2w,2w+1
        int c4  = (l & 31) * 4;             // 4-short group
        s16x4 v = *(const s16x4*)(mbs + row * 128 + c4);
        int s   = po * 32 + (c4 >> 2);
        *(s16x4*)&dstb[row * 256 + ((s ^ (9 * (row & 7))) << 2)] = v;
    };

    // ---- step 1: h1 = update(xg), publish ----
#pragma unroll
    for (int j = 0; j < 4; ++j) acc4[j] = xg[j];
    update(hbuf[1], mb_me + 1 * 2048);
    __threadfence();
    __syncthreads();
    if (tid == 0) astore_rel(rdy_me, 1);

    f32x4 accy;

    // ---- main loop, templated on own-kk base so whr[] indices are static ----
    auto mainloop = [&](auto OBc) {
        constexpr int OB = decltype(OBc)::v;        // own kk base (0 or 4)
        constexpr int PB = 4 - OB;                  // partner kk base

        auto gphase = [&](auto KKc, auto SEEDc, const short* curb) {
            constexpr int kk   = decltype(KKc)::v;
            constexpr int seed = decltype(SEEDc)::v;
            bf16x8 a  = loadA(curb, kk);
            bf16x8 wf = *(const bf16x8*)&woutl[wid][kk][l * 8];
            if constexpr (seed)
                accy = __builtin_amdgcn_mfma_f32_16x16x32_bf16(a, wf, (f32x4){by, by, by, by}, 0, 0, 0);
            else
                accy = __builtin_amdgcn_mfma_f32_16x16x32_bf16(a, wf, accy, 0, 0, 0);
#pragma unroll
            for (int j = 0; j < 4; ++j) {
                if constexpr (seed)
                    acc4[j] = __builtin_amdgcn_mfma_f32_16x16x32_bf16(a, whr[kk][j], xg[j], 0, 0, 0);
                else
                    acc4[j] = __builtin_amdgcn_mfma_f32_16x16x32_bf16(a, whr[kk][j], acc4[j], 0, 0, 0);
            }
        };

        for (int t = 2; t <= T; ++t) {
            short* curb = hbuf[(t - 1) & 1];
            short* nxtb = hbuf[t & 1];

            // own-half kk phases (no wait needed)
            gphase(ic<OB + 0>{}, ic<1>{}, curb);
            gphase(ic<OB + 1>{}, ic<0>{}, curb);
            gphase(ic<OB + 2>{}, ic<0>{}, curb);
            gphase(ic<OB + 3>{}, ic<0>{}, curb);

            // partner h-half: poll ready, stage into curb
            if (tid == 0) {
                while (aload_acq(rdy_pt) < t - 1) __builtin_amdgcn_s_sleep(2);
            }
            __syncthreads();
            stage_partner(curb, mb_pt + ((t - 1) & 1) * 2048);
            __syncthreads();
            if (tid == 0) astore_rel(ack_pt, t - 1);   // consumed partner slot t-1

            // partner-half kk phases
            gphase(ic<PB + 0>{}, ic<0>{}, curb);
            gphase(ic<PB + 1>{}, ic<0>{}, curb);
            gphase(ic<PB + 2>{}, ic<0>{}, curb);
            gphase(ic<PB + 3>{}, ic<0>{}, curb);

            // store y_{t-2} = h_{t-1} @ Wout^T + b_out
            {
                float* yp = Y + ((size_t)(t - 2) * Btot + row0 + 4 * g4) * 128 + wid * 16 + l15;
#pragma unroll
                for (int rr = 0; rr < 4; ++rr)
                    __builtin_nontemporal_store(accy[rr], yp + (size_t)rr * 128);
            }

            // producer: wait partner consumed slot t-2 before overwriting t&1
            if (tid == 0) {
                while (aload_acq(ack_me) < t - 2) __builtin_amdgcn_s_sleep(2);
            }
            __syncthreads();
            update(nxtb, mb_me + (t & 1) * 2048);
            __threadfence();
            __syncthreads();
            if (tid == 0) astore_rel(rdy_me, t);
        }
    };

    if (ho == 0) mainloop(ic<0>{});
    else         mainloop(ic<4>{});

    // ---- epilogue: y_{T-1} = h_T @ Wout^T + b_out (needs partner h_T) ----
    {
        short* curb = hbuf[T & 1];
        if (tid == 0) {
            while (aload_acq(rdy_pt) < T) __builtin_amdgcn_s_sleep(2);
        }
        __syncthreads();
        stage_partner(curb, mb_pt + (T & 1) * 2048);
        __syncthreads();

        accy = (f32x4){by, by, by, by};
#pragma unroll
        for (int kk = 0; kk < 8; ++kk) {
            bf16x8 a  = loadA(curb, kk);
            bf16x8 wf = *(const bf16x8*)&woutl[wid][kk][l * 8];
            accy = __builtin_amdgcn_mfma_f32_16x16x32_bf16(a, wf, accy, 0, 0, 0);
        }
        float* yp = Y + ((size_t)(T - 1) * Btot + row0 + 4 * g4) * 128 + wid * 16 + l15;
#pragma unroll
        for (int rr = 0; rr < 4; ++rr)
            __builtin_nontemporal_store(accy[rr], yp + (size_t)rr * 128);
    }
}

extern "C" void kernel_launch(void* const* d_in, const int* in_sizes, int n_in,
                              void* d_out, int out_size, void* d_ws, size_t ws_size,
                              hipStream_t stream) {
    const float* C     = (const float*)d_in[0];
    const float* W_ih  = (const float*)d_in[1];
    const float* W_hh  = (const float*)d_in[2];
    const float* b_ih  = (const float*)d_in[3];
    const float* b_hh  = (const float*)d_in[4];
    const float* W_out = (const float*)d_in[5];
    const float* b_out = (const float*)d_in[6];

    const int H    = 256;
    const int Btot = in_sizes[0] / H;     // 2048
    const int O    = in_sizes[5] / H;     // 128
    const int T    = out_size / (Btot * O);

    char* ws = (char*)d_ws;
    unsigned short* Whh_p  = (unsigned short*)(ws);                    // 512 KB
    unsigned short* Wih_p  = (unsigned short*)(ws + (512 << 10));      // 512 KB
    unsigned short* Wout_p = (unsigned short*)(ws + (1024 << 10));     // 64 KB
    unsigned short* mbox   = (unsigned short*)(ws + (2048 << 10));     // 2 MB
    int*            ready  = (int*)(ws + (4096 << 10));                // 32 KB
    int*            ackf   = (int*)(ws + (4096 << 10) + (32 << 10));   // 32 KB

    hipMemsetAsync(ws + (4096 << 10), 0, 64 << 10, stream);
    hipLaunchKernelGGL(pack_w_gates, dim3(128), dim3(256), 0, stream, W_hh, Whh_p);
    hipLaunchKernelGGL(pack_w_gates, dim3(128), dim3(256), 0, stream, W_ih, Wih_p);
    hipLaunchKernelGGL(pack_w_out,  dim3(16),  dim3(256), 0, stream, W_out, Wout_p);
    hipLaunchKernelGGL(lstm_main, dim3(2 * Btot / 16), dim3(512), 0, stream,
                       C, Wih_p, Whh_p, Wout_p, b_ih, b_hh, b_out,
                       (float*)d_out, mbox, ready, ackf, T, Btot);
}

// Round 6
// 653.357 us; speedup vs baseline: 9.8250x; 9.8250x over previous
//
#include <hip/hip_runtime.h>
#include <hip/hip_bf16.h>

typedef __attribute__((ext_vector_type(8))) short  bf16x8;
typedef __attribute__((ext_vector_type(4))) short  s16x4;
typedef __attribute__((ext_vector_type(4))) float  f32x4;

#define LOG2E 1.44269504088896340736f
template<int N> struct ic { static constexpr int v = N; };

__device__ __forceinline__ unsigned short f2bf(float x) {
    union { float f; unsigned int u; } v; v.f = x;
    unsigned int u = v.u;
    u += 0x7fffu + ((u >> 16) & 1u);          // round-to-nearest-even
    return (unsigned short)(u >> 16);
}
__device__ __forceinline__ float fast_sigmoid(float x) {
    float e = __builtin_amdgcn_exp2f(-LOG2E * x);
    return __builtin_amdgcn_rcpf(1.0f + e);
}
__device__ __forceinline__ float fast_tanh(float x) {
    float e = __builtin_amdgcn_exp2f(2.0f * LOG2E * x);
    return 1.0f - 2.0f * __builtin_amdgcn_rcpf(1.0f + e);
}

// ---------------------------------------------------------------------------
// Pack [1024 x 256] fp32 weight into bf16 MFMA-B-fragment-major layout.
//   fid = w*64 + kk*8 + j ; dst[(fid*64+lane)*8+e] = bf16(W[R][k])
//   R = g*256 + w*32 + tn*16 + (lane&15), j = g*2+tn
//   k = kk*32 + 4*(lane>>4) + (e&3) + 16*(e>>2)
// ---------------------------------------------------------------------------
__global__ void pack_w_big(const float* __restrict__ W, unsigned short* __restrict__ dst) {
    int idx  = blockIdx.x * 256 + threadIdx.x;   // 0..32767
    int lane = idx & 63;
    int fid  = idx >> 6;                         // 0..511
    int j    = fid & 7;
    int kk   = (fid >> 3) & 7;
    int w    = fid >> 6;
    int g    = j >> 1, tn = j & 1;
    int R    = g * 256 + w * 32 + tn * 16 + (lane & 15);
    int kb   = kk * 32 + 4 * (lane >> 4);
    const float* src = W + (size_t)R * 256 + kb;
    union { unsigned short s[8]; uint4 v; } u;
#pragma unroll
    for (int e = 0; e < 8; ++e) {
        int k = (e & 3) + 16 * (e >> 2);
        u.s[e] = f2bf(src[k]);
    }
    *(uint4*)(dst + (size_t)idx * 8) = u.v;
}

// W_out [128 x 256]: fid = wv*8 + kk, R = wv*16 + (lane&15)
__global__ void pack_w_out(const float* __restrict__ W, unsigned short* __restrict__ dst) {
    int idx  = blockIdx.x * 256 + threadIdx.x;   // 0..4095
    int lane = idx & 63;
    int fid  = idx >> 6;
    int kk   = fid & 7;
    int wv   = fid >> 3;
    int R    = wv * 16 + (lane & 15);
    int kb   = kk * 32 + 4 * (lane >> 4);
    const float* src = W + (size_t)R * 256 + kb;
    union { unsigned short s[8]; uint4 v; } u;
#pragma unroll
    for (int e = 0; e < 8; ++e) {
        int k = (e & 3) + 16 * (e >> 2);
        u.s[e] = f2bf(src[k]);
    }
    *(uint4*)(dst + (size_t)idx * 8) = u.v;
}

// ---------------------------------------------------------------------------
// Gates-only persistent LSTM. 128 blocks x 512 thr (8 waves). Wave w owns
// gate strip [w*32,+32) x {i,f,g,o}. h_t (bf16) written to H (= d_out, in
// place; y computed later by out_gemm). Whh: kk0..3 register-resident,
// kk4 LDS-parked, kk5..7 streamed through a per-wave 64KB LDS ring via
// global_load_lds with counted vmcnt(4) (never drained in-loop); next-step
// kk5 prefetch crosses a raw s_barrier.
// ---------------------------------------------------------------------------
__global__ __launch_bounds__(512) __attribute__((amdgpu_waves_per_eu(2, 2)))
void lstm_gates(const float* __restrict__ C,
                const unsigned short* __restrict__ Wih_p,
                const unsigned short* __restrict__ Whh_p,
                const float* __restrict__ b_ih,
                const float* __restrict__ b_hh,
                unsigned short* __restrict__ H,
                int T, int Btot)
{
    __shared__ short hbuf[2][4096];     // 16 KB h double-buffer
    __shared__ short park[8][8][512];   // 64 KB kk4 B-frags (per wave)
    __shared__ short ring[8][8][512];   // 64 KB stream ring: slot j <-> frag j

    const int tid  = threadIdx.x;
    const int l    = tid & 63;
    const int wid  = tid >> 6;
    const int l15  = l & 15;
    const int g4   = l >> 4;
    const int row0 = blockIdx.x * 16;

    const unsigned short* wib = Wih_p + (size_t)wid * 32768;
    const unsigned short* whb = Whh_p + (size_t)wid * 32768;

    // ---- stage C tile -> hbuf[0] (bf16, swizzled 8B slots) ----
    {
        int r  = tid >> 5;
        int cb = tid & 31;
        const float* src = C + (size_t)(row0 + r) * 256 + cb * 8;
        float4 f0 = *(const float4*)(src);
        float4 f1 = *(const float4*)(src + 4);
        int m  = 9 * (r & 7);
        int s0 = cb * 2;
        short* hb = hbuf[0] + r * 256;
        union { unsigned short s[4]; unsigned long long v; } p0, p1;
        p0.s[0] = f2bf(f0.x); p0.s[1] = f2bf(f0.y); p0.s[2] = f2bf(f0.z); p0.s[3] = f2bf(f0.w);
        p1.s[0] = f2bf(f1.x); p1.s[1] = f2bf(f1.y); p1.s[2] = f2bf(f1.z); p1.s[3] = f2bf(f1.w);
        *(unsigned long long*)(hb + ((s0 ^ m) * 4))       = p0.v;
        *(unsigned long long*)(hb + (((s0 + 1) ^ m) * 4)) = p1.v;
    }

    auto issue = [&](short (*dst)[512], int kk, int j) {
        const unsigned short* src = whb + (((size_t)kk * 8 + j) * 64 + l) * 8;
        __builtin_amdgcn_global_load_lds(
            (const __attribute__((address_space(1))) void*)src,
            (__attribute__((address_space(3))) void*)&dst[j][0], 16, 0, 0);
    };
#pragma unroll
    for (int j = 0; j < 8; ++j) issue(park[wid], 4, j);
#pragma unroll
    for (int j = 0; j < 8; ++j) issue(ring[wid], 5, j);

    // A-frag loader: row = l&15, k = kk*32 + 4*(l>>4) + {0..3,16..19}
    const int msw = 9 * (l15 & 7);
    auto loadA = [&](const short* buf, int kk) -> bf16x8 {
        int slo = kk * 8 + g4;
        const short* base = buf + l15 * 256;
        s16x4 lo = *(const s16x4*)(base + ((slo ^ msw) * 4));
        s16x4 hi = *(const s16x4*)(base + (((slo + 4) ^ msw) * 4));
        bf16x8 a;
        a[0] = lo[0]; a[1] = lo[1]; a[2] = lo[2]; a[3] = lo[3];
        a[4] = hi[0]; a[5] = hi[1]; a[6] = hi[2]; a[7] = hi[3];
        return a;
    };
    auto loadB = [&](const unsigned short* wb, int kk, int j) -> bf16x8 {
        return *(const bf16x8*)(wb + (((size_t)kk * 8 + j) * 64 + l) * 8);
    };

    __syncthreads();   // C tile + park + ring(kk5) staged (one-time drain)

    // ---- acc = x_gates = C @ Wih^T + b_ih + b_hh ----
    f32x4 acc[8];
#pragma unroll
    for (int j = 0; j < 8; ++j) acc[j] = (f32x4){0.f, 0.f, 0.f, 0.f};
#pragma unroll
    for (int kk = 0; kk < 8; ++kk) {
        bf16x8 a = loadA(hbuf[0], kk);
#pragma unroll
        for (int j = 0; j < 8; ++j)
            acc[j] = __builtin_amdgcn_mfma_f32_16x16x32_bf16(a, loadB(wib, kk, j), acc[j], 0, 0, 0);
    }
#pragma unroll
    for (int j = 0; j < 8; ++j) {
        int g = j >> 1, tn = j & 1;
        int col = g * 256 + wid * 32 + tn * 16 + l15;
        float bias = b_ih[col] + b_hh[col];
        acc[j] = acc[j] + bias;
    }
    // pack x_gates to bf16 (persistent, 16 regs)
    unsigned xgp[16];
#pragma unroll
    for (int j = 0; j < 8; ++j) {
        xgp[2 * j]     = (unsigned)f2bf(acc[j][0]) | ((unsigned)f2bf(acc[j][1]) << 16);
        xgp[2 * j + 1] = (unsigned)f2bf(acc[j][2]) | ((unsigned)f2bf(acc[j][3]) << 16);
    }
    auto xgu = [&](int j) -> f32x4 {
        union { unsigned u; float f; } c0, c1, c2, c3;
        unsigned u0 = xgp[2 * j], u1 = xgp[2 * j + 1];
        c0.u = u0 << 16; c1.u = u0 & 0xffff0000u;
        c2.u = u1 << 16; c3.u = u1 & 0xffff0000u;
        return (f32x4){c0.f, c1.f, c2.f, c3.f};
    };

    // ---- Whh kk0..3 register-resident (128 VGPR) ----
    bf16x8 whr[4][8];
#pragma unroll
    for (int kk = 0; kk < 4; ++kk)
#pragma unroll
        for (int j = 0; j < 8; ++j) whr[kk][j] = loadB(whb, kk, j);

    float cst[8];
#pragma unroll
    for (int i = 0; i < 8; ++i) cst[i] = 0.f;

    // cell update -> h into nxtb (swz LDS) + H global (plain rows)
    auto update_write = [&](short* nxtb, unsigned short* hst) {
#pragma unroll
        for (int tn = 0; tn < 2; ++tn) {
#pragma unroll
            for (int rr = 0; rr < 4; ++rr) {
                float iv = fast_sigmoid(acc[0 + tn][rr]);
                float fv = fast_sigmoid(acc[2 + tn][rr]);
                float gv = fast_tanh(acc[4 + tn][rr]);
                float ov = fast_sigmoid(acc[6 + tn][rr]);
                float cn = fv * cst[tn * 4 + rr] + iv * gv;
                cst[tn * 4 + rr] = cn;
                float hn = ov * fast_tanh(cn);
                unsigned short hb = f2bf(hn);
                int row = 4 * g4 + rr;
                int col = wid * 32 + tn * 16 + l15;
                int ps  = (col >> 2) ^ (9 * (row & 7));
                nxtb[row * 256 + ps * 4 + (col & 3)] = (short)hb;
                hst[(size_t)row * 256 + col] = hb;
            }
        }
    };

    // ---- t = 1: gates = x_gates (h0 = 0); h1 -> hbuf[1], H[0] ----
    update_write(hbuf[1], H + (size_t)row0 * 256);
    __syncthreads();

    // ---- phase lambdas ----
    auto phaseR0 = [&](const short* curb) {
        bf16x8 a = loadA(curb, 0);
#pragma unroll
        for (int j = 0; j < 8; ++j)
            acc[j] = __builtin_amdgcn_mfma_f32_16x16x32_bf16(a, whr[0][j], xgu(j), 0, 0, 0);
    };
    auto phaseR = [&](auto KK, const short* curb) {
        constexpr int kk = decltype(KK)::v;
        bf16x8 a = loadA(curb, kk);
#pragma unroll
        for (int j = 0; j < 8; ++j)
            acc[j] = __builtin_amdgcn_mfma_f32_16x16x32_bf16(a, whr[kk][j], acc[j], 0, 0, 0);
    };
    auto phaseP = [&](const short* curb) {
        bf16x8 a = loadA(curb, 4);
#pragma unroll
        for (int j = 0; j < 8; ++j) {
            bf16x8 b = *(const bf16x8*)&park[wid][j][l * 8];
            acc[j] = __builtin_amdgcn_mfma_f32_16x16x32_bf16(a, b, acc[j], 0, 0, 0);
        }
    };
    auto phaseS = [&](auto KK, auto NX, const short* curb) {
        constexpr int kk = decltype(KK)::v;
        constexpr int nx = decltype(NX)::v;
        bf16x8 a = loadA(curb, kk);
        asm volatile("s_waitcnt vmcnt(4)" ::: "memory");
#pragma unroll
        for (int j = 0; j < 4; ++j) {
            bf16x8 b = *(const bf16x8*)&ring[wid][j][l * 8];
            acc[j] = __builtin_amdgcn_mfma_f32_16x16x32_bf16(a, b, acc[j], 0, 0, 0);
        }
#pragma unroll
        for (int j = 0; j < 4; ++j) issue(ring[wid], nx, j);
        asm volatile("s_waitcnt vmcnt(4)" ::: "memory");
#pragma unroll
        for (int j = 4; j < 8; ++j) {
            bf16x8 b = *(const bf16x8*)&ring[wid][j][l * 8];
            acc[j] = __builtin_amdgcn_mfma_f32_16x16x32_bf16(a, b, acc[j], 0, 0, 0);
        }
#pragma unroll
        for (int j = 4; j < 8; ++j) issue(ring[wid], nx, j);
    };

    // ---- main loop: compute h_t for t = 2..T ----
    for (int t = 2; t <= T; ++t) {
        const short* curb = hbuf[(t - 1) & 1];
        short*       nxtb = hbuf[t & 1];

        phaseR0(curb);
        phaseR(ic<1>{}, curb);
        phaseR(ic<2>{}, curb);
        phaseR(ic<3>{}, curb);
        phaseP(curb);
        phaseS(ic<5>{}, ic<6>{}, curb);   // consume kk5, prefetch kk6
        phaseS(ic<6>{}, ic<7>{}, curb);   // consume kk6, prefetch kk7
        phaseS(ic<7>{}, ic<5>{}, curb);   // consume kk7, prefetch next-step kk5

        update_write(nxtb, H + ((size_t)(t - 1) * Btot + row0) * 256);

        // raw barrier: h LDS writes visible; ring prefetch stays in flight
        asm volatile("s_waitcnt lgkmcnt(0)" ::: "memory");
        __builtin_amdgcn_sched_barrier(0);
        __builtin_amdgcn_s_barrier();
    }
}

// ---------------------------------------------------------------------------
// Y[s][b][:] = H[s][b][:] @ Wout^T + b_out, IN PLACE (H bf16 row = 512 B =
// Y f32 row). Each wave reads only its own 32 rows then overwrites them.
// ---------------------------------------------------------------------------
__global__ __launch_bounds__(512) void out_gemm(
    const unsigned short* __restrict__ Wout_p,
    const float* __restrict__ b_out,
    float* __restrict__ Y)
{
    const int tid = threadIdx.x;
    const int l   = tid & 63;
    const int w   = tid >> 6;
    const int l15 = l & 15;
    const int g4  = l >> 4;
    const size_t rw0 = (size_t)blockIdx.x * 256 + w * 32;
    const unsigned short* Hp = (const unsigned short*)Y;

    bf16x8 a[2][8];
#pragma unroll
    for (int rt = 0; rt < 2; ++rt)
#pragma unroll
        for (int kk = 0; kk < 8; ++kk) {
            const unsigned short* src = Hp + (rw0 + rt * 16 + l15) * 256 + kk * 32 + 4 * g4;
            s16x4 lo = *(const s16x4*)(src);
            s16x4 hi = *(const s16x4*)(src + 16);
            bf16x8 v;
            v[0] = lo[0]; v[1] = lo[1]; v[2] = lo[2]; v[3] = lo[3];
            v[4] = hi[0]; v[5] = hi[1]; v[6] = hi[2]; v[7] = hi[3];
            a[rt][kk] = v;
        }

    f32x4 acc[2][8];
#pragma unroll
    for (int rt = 0; rt < 2; ++rt)
#pragma unroll
        for (int wv = 0; wv < 8; ++wv) acc[rt][wv] = (f32x4){0.f, 0.f, 0.f, 0.f};

#pragma unroll
    for (int kk = 0; kk < 8; ++kk)
#pragma unroll
        for (int wv = 0; wv < 8; ++wv) {
            bf16x8 wf = *(const bf16x8*)(Wout_p + ((size_t)(wv * 8 + kk) * 64 + l) * 8);
            acc[0][wv] = __builtin_amdgcn_mfma_f32_16x16x32_bf16(a[0][kk], wf, acc[0][wv], 0, 0, 0);
            acc[1][wv] = __builtin_amdgcn_mfma_f32_16x16x32_bf16(a[1][kk], wf, acc[1][wv], 0, 0, 0);
        }

#pragma unroll
    for (int wv = 0; wv < 8; ++wv) {
        float by = b_out[wv * 16 + l15];
#pragma unroll
        for (int rt = 0; rt < 2; ++rt)
#pragma unroll
            for (int i = 0; i < 4; ++i)
                Y[(rw0 + rt * 16 + 4 * g4 + i) * 128 + wv * 16 + l15] = acc[rt][wv][i] + by;
    }
}

extern "C" void kernel_launch(void* const* d_in, const int* in_sizes, int n_in,
                              void* d_out, int out_size, void* d_ws, size_t ws_size,
                              hipStream_t stream) {
    const float* C     = (const float*)d_in[0];
    const float* W_ih  = (const float*)d_in[1];
    const float* W_hh  = (const float*)d_in[2];
    const float* b_ih  = (const float*)d_in[3];
    const float* b_hh  = (const float*)d_in[4];
    const float* W_out = (const float*)d_in[5];
    const float* b_out = (const float*)d_in[6];

    const int H    = 256;
    const int Btot = in_sizes[0] / H;     // 2048
    const int O    = in_sizes[5] / H;     // 128
    const int T    = out_size / (Btot * O);

    unsigned short* Whh_p  = (unsigned short*)d_ws;          // 512 KB
    unsigned short* Wih_p  = Whh_p + (1 << 18);              // 512 KB
    unsigned short* Wout_p = Wih_p + (1 << 18);              // 64 KB

    hipLaunchKernelGGL(pack_w_big, dim3(128), dim3(256), 0, stream, W_hh, Whh_p);
    hipLaunchKernelGGL(pack_w_big, dim3(128), dim3(256), 0, stream, W_ih, Wih_p);
    hipLaunchKernelGGL(pack_w_out, dim3(16),  dim3(256), 0, stream, W_out, Wout_p);
    hipLaunchKernelGGL(lstm_gates, dim3(Btot / 16), dim3(512), 0, stream,
                       C, Wih_p, Whh_p, b_ih, b_hh,
                       (unsigned short*)d_out, T, Btot);
    hipLaunchKernelGGL(out_gemm, dim3((T * Btot) / 256), dim3(512), 0, stream,
                       Wout_p, b_out, (float*)d_out);
}